// Round 10
// baseline (126.583 us; speedup 1.0000x reference)
//
#include <hip/hip_runtime.h>
#include <hip/hip_bf16.h>

// ---------------------------------------------------------------------------
// CrossAttention: out = softmax((x Wq)(ctx Wk)^T * scale) (ctx Wv) Wo
// B=2, N=M=2048, H=16, D=64, QD=INNER=1024. fp32 in/out, bf16 MFMA inside.
// R10: GEMMs get counted-vmcnt pipeline (T3/T4-lite): 3 LDS buffer sets,
// depth-2 prefetch, raw s_barrier + s_waitcnt vmcnt(4) — prefetch loads stay
// in flight ACROSS barriers (no vmcnt(0) drain per K-step).
// Attention unchanged from R7.
// ---------------------------------------------------------------------------

typedef __attribute__((ext_vector_type(8))) __bf16    bf16x8;
typedef __attribute__((ext_vector_type(4))) __bf16    bf16x4;
typedef __attribute__((ext_vector_type(4))) float     f32x4;

#define B_    2
#define H_    16
#define N_    2048
#define M_    2048
#define D_    64
#define QD_   1024

// 0.125 * log2(e): folds softmax scale and exp->exp2 conversion into Q
#define QSCALE 0.18033688011112042f

// direct global->LDS async copy, 16B per lane; LDS dest = wave-uniform base + lane*16
__device__ __forceinline__ void gld16(const __bf16* g, __bf16* l) {
    __builtin_amdgcn_global_load_lds(
        (const __attribute__((address_space(1))) unsigned int*)(g),
        (__attribute__((address_space(3))) unsigned int*)(l), 16, 0, 0);
}

// ---------------------------------------------------------------------------
// fused f32->bf16 convert for x (z=0) and context (z=1)
// ---------------------------------------------------------------------------
__global__ __launch_bounds__(256) void cvt2_f32_bf16(const float* __restrict__ x,
                                                     const float* __restrict__ ctx,
                                                     __bf16* __restrict__ xb,
                                                     __bf16* __restrict__ cb) {
    const float* src = blockIdx.y ? ctx : x;
    __bf16*      dst = blockIdx.y ? cb  : xb;
    int i = (blockIdx.x * 256 + threadIdx.x) * 4;
    float4 v = *reinterpret_cast<const float4*>(src + i);
    bf16x4 o;
    o.x = (__bf16)v.x; o.y = (__bf16)v.y; o.z = (__bf16)v.z; o.w = (__bf16)v.w;
    *reinterpret_cast<bf16x4*>(dst + i) = o;
}

// ---------------------------------------------------------------------------
// fused weight transpose+convert: Wt[o][i] = W[i][o], z selects which weight
// ---------------------------------------------------------------------------
__global__ __launch_bounds__(256) void transpose4_cvt(const float* __restrict__ w0,
                                                      const float* __restrict__ w1,
                                                      const float* __restrict__ w2,
                                                      const float* __restrict__ w3,
                                                      __bf16* __restrict__ t0,
                                                      __bf16* __restrict__ t1,
                                                      __bf16* __restrict__ t2,
                                                      __bf16* __restrict__ t3) {
    __shared__ float tile[64][65];
    const int z = blockIdx.z;
    const float* in = (z == 0) ? w0 : (z == 1) ? w1 : (z == 2) ? w2 : w3;
    __bf16*     out = (z == 0) ? t0 : (z == 1) ? t1 : (z == 2) ? t2 : t3;
    const int i0 = blockIdx.x * 64;
    const int o0 = blockIdx.y * 64;
    const int t  = threadIdx.x;
    const int r  = t >> 4;
    const int c4 = (t & 15) * 4;
#pragma unroll
    for (int p = 0; p < 4; ++p) {
        int row = p * 16 + r;
        float4 v = *reinterpret_cast<const float4*>(in + (size_t)(i0 + row) * QD_ + o0 + c4);
        tile[row][c4 + 0] = v.x; tile[row][c4 + 1] = v.y;
        tile[row][c4 + 2] = v.z; tile[row][c4 + 3] = v.w;
    }
    __syncthreads();
#pragma unroll
    for (int p = 0; p < 4; ++p) {
        int orow = p * 16 + r;
        bf16x4 o;
        o.x = (__bf16)tile[c4 + 0][orow];
        o.y = (__bf16)tile[c4 + 1][orow];
        o.z = (__bf16)tile[c4 + 2][orow];
        o.w = (__bf16)tile[c4 + 3][orow];
        *reinterpret_cast<bf16x4*>(out + (size_t)(o0 + orow) * QD_ + i0 + c4) = o;
    }
}

// ---------------------------------------------------------------------------
// GEMM core R10: 128x128 tile, 4 waves (2x2), wave = 64x64 (4x4 frags), BK=32.
// 3 LDS buffer sets (48 KB), depth-2 counted-vmcnt pipeline:
//   prologue: stage(0), stage(1)
//   iter t:  s_waitcnt vmcnt(4)   [tile t done; tile t+1 stays in flight]
//            s_barrier            [raw - no drain]
//            stage(t+2)           [buf (t+2)%3, safe: compute(t-1) done]
//            compute(t)           [buf t%3]
// XOR granule swizzle on both operands (pre-swizzled source, swizzled read).
// ---------------------------------------------------------------------------
#define GEMM_BODY(A_, Bt_)                                                                     \
    __shared__ __align__(16) __bf16 Alds[3][128 * 32];                                         \
    __shared__ __align__(16) __bf16 Blds[3][128 * 32];                                         \
    const int tid  = threadIdx.x;                                                              \
    const int wid  = tid >> 6;                                                                 \
    const int lane = tid & 63;                                                                 \
    const int l15  = lane & 15;                                                                \
    const int lg   = lane >> 4;                                                                \
    const int wr   = wid >> 1;                                                                 \
    const int wc   = wid & 1;                                                                  \
    const int rowBase = blockIdx.x * 128;                                                      \
    const int colBase = blockIdx.y * 128;                                                      \
    const int srow = wid * 32 + (lane >> 2);                                                   \
    const int sg   = ((lane & 3) ^ ((srow >> 1) & 3)) * 8;  /* pre-swizzled src granule */     \
    const __bf16* Ag  = A_  + (size_t)(rowBase + srow) * QD_ + sg;                             \
    const __bf16* Ag2 = Ag  + (size_t)16 * QD_;                                                \
    const __bf16* Bg  = Bt_ + (size_t)(colBase + srow) * QD_ + sg;                             \
    const __bf16* Bg2 = Bg  + (size_t)16 * QD_;                                                \
    const int sOff  = (wid * 32) * 32;                                                         \
    const int sOff2 = sOff + 16 * 32;                                                          \
    int aoff[4], boff[4];                                                                      \
    _Pragma("unroll")                                                                          \
    for (int m = 0; m < 4; ++m) {                                                              \
        int ra = wr * 64 + m * 16 + l15;                                                       \
        int rb = wc * 64 + m * 16 + l15;                                                       \
        aoff[m] = ra * 32 + ((lg ^ ((ra >> 1) & 3)) * 8);                                      \
        boff[m] = rb * 32 + ((lg ^ ((rb >> 1) & 3)) * 8);                                      \
    }                                                                                          \
    f32x4 acc[4][4] = {};                                                                      \
    /* prologue: stage tiles 0 and 1 */                                                        \
    gld16(Ag,            &Alds[0][sOff]);                                                      \
    gld16(Ag2,           &Alds[0][sOff2]);                                                     \
    gld16(Bg,            &Blds[0][sOff]);                                                      \
    gld16(Bg2,           &Blds[0][sOff2]);                                                     \
    gld16(Ag  + 32,      &Alds[1][sOff]);                                                      \
    gld16(Ag2 + 32,      &Alds[1][sOff2]);                                                     \
    gld16(Bg  + 32,      &Blds[1][sOff]);                                                      \
    gld16(Bg2 + 32,      &Blds[1][sOff2]);                                                     \
    int cur = 0, nxt2 = 2;                                                                     \
    for (int t = 0; t < 32; ++t) {                                                             \
        if (t != 31) { asm volatile("s_waitcnt vmcnt(4)" ::: "memory"); }                      \
        else         { asm volatile("s_waitcnt vmcnt(0)" ::: "memory"); }                      \
        __builtin_amdgcn_s_barrier();                                                          \
        if (t + 2 < 32) {                                                                      \
            int kn = (t + 2) * 32;                                                             \
            gld16(Ag  + kn, &Alds[nxt2][sOff]);                                                \
            gld16(Ag2 + kn, &Alds[nxt2][sOff2]);                                               \
            gld16(Bg  + kn, &Blds[nxt2][sOff]);                                                \
            gld16(Bg2 + kn, &Blds[nxt2][sOff2]);                                               \
        }                                                                                      \
        GCOMPUTE(cur)                                                                          \
        cur = (cur == 2) ? 0 : cur + 1;                                                        \
        nxt2 = (nxt2 == 2) ? 0 : nxt2 + 1;                                                     \
    }

#define GCOMPUTE(BUF)                                                                          \
    {                                                                                          \
        bf16x8 a[4], b[4];                                                                     \
        _Pragma("unroll")                                                                      \
        for (int m = 0; m < 4; ++m)                                                            \
            a[m] = *reinterpret_cast<const bf16x8*>(&Alds[BUF][aoff[m]]);                      \
        _Pragma("unroll")                                                                      \
        for (int n = 0; n < 4; ++n)                                                            \
            b[n] = *reinterpret_cast<const bf16x8*>(&Blds[BUF][boff[n]]);                      \
        _Pragma("unroll")                                                                      \
        for (int m = 0; m < 4; ++m)                                                            \
            _Pragma("unroll")                                                                  \
            for (int n = 0; n < 4; ++n)                                                        \
                acc[m][n] = __builtin_amdgcn_mfma_f32_16x16x32_bf16(a[m], b[n], acc[m][n], 0, 0, 0); \
    }

// fused Q/K/V projection: blockIdx.z selects {Q (scaled), K, V^T} output
__global__ __launch_bounds__(256) void gemm_qkv(const __bf16* __restrict__ xb,
                                                const __bf16* __restrict__ cb,
                                                const __bf16* __restrict__ Wtq,
                                                const __bf16* __restrict__ Wtk,
                                                const __bf16* __restrict__ Wtv,
                                                __bf16* __restrict__ Qb,
                                                __bf16* __restrict__ Kb,
                                                __bf16* __restrict__ Vt) {
    const int z = blockIdx.z;
    const __bf16* Asel = (z == 0) ? xb : cb;
    const __bf16* Bsel = (z == 0) ? Wtq : (z == 1) ? Wtk : Wtv;
    GEMM_BODY(Asel, Bsel)
#pragma unroll
    for (int m = 0; m < 4; ++m)
#pragma unroll
        for (int n = 0; n < 4; ++n)
#pragma unroll
            for (int r = 0; r < 4; ++r) {
                int rr = rowBase + wr * 64 + m * 16 + lg * 4 + r;
                int cc = colBase + wc * 64 + n * 16 + l15;
                float v = acc[m][n][r];
                int b_ = rr >> 11, nn = rr & 2047, hh = cc >> 6, dd = cc & 63;
                if (z == 0) {
                    Qb[((size_t)(b_ * H_ + hh) * N_ + nn) * D_ + dd] = (__bf16)(v * QSCALE);
                } else if (z == 1) {
                    Kb[((size_t)(b_ * H_ + hh) * N_ + nn) * D_ + dd] = (__bf16)v;
                } else {
                    Vt[((size_t)(b_ * H_ + hh) * D_ + dd) * M_ + nn] = (__bf16)v;
                }
            }
}

// final projection: AO @ Wto -> f32 out
__global__ __launch_bounds__(256) void gemm_out(const __bf16* __restrict__ AO,
                                                const __bf16* __restrict__ Wto,
                                                float* __restrict__ out) {
    GEMM_BODY(AO, Wto)
#pragma unroll
    for (int m = 0; m < 4; ++m)
#pragma unroll
        for (int n = 0; n < 4; ++n)
#pragma unroll
            for (int r = 0; r < 4; ++r) {
                int rr = rowBase + wr * 64 + m * 16 + lg * 4 + r;
                int cc = colBase + wc * 64 + n * 16 + l15;
                out[(size_t)rr * QD_ + cc] = acc[m][n][r];
            }
}

// ---------------------------------------------------------------------------
// Attention (R7, unchanged). Grid 512 (XCD-swizzled), 8 waves x 16 q-rows,
// K/V LDS dbuf (32 KB), XOR swizzle via pre-swizzled global source, swapped
// QK^T -> P lane-local, row-sums via ones-MFMA, exp2 with pre-scaled Q.
// ---------------------------------------------------------------------------
__global__ __launch_bounds__(512, 4) void attn_kernel(const __bf16* __restrict__ Q,
                                                      const __bf16* __restrict__ K,
                                                      const __bf16* __restrict__ Vt,
                                                      __bf16* __restrict__ AO) {
    __shared__ __align__(16) __bf16 Klds[2][4096];
    __shared__ __align__(16) __bf16 Vlds[2][4096];

    const int logical = (blockIdx.x & 7) * 64 + (blockIdx.x >> 3);
    const int qt   = logical & 15;
    const int bh   = logical >> 4;
    const int b    = bh >> 4;
    const int h    = bh & 15;
    const int wid  = threadIdx.x >> 6;     // 0..7
    const int lane = threadIdx.x & 63;
    const int l15  = lane & 15;
    const int lg   = lane >> 4;
    const int qbase = qt * 128 + wid * 16;

    const __bf16* Qp = Q  + ((size_t)bh * N_ + qbase) * D_;
    const __bf16* Kp = K  + (size_t)bh * M_ * D_;
    const __bf16* Vp = Vt + (size_t)bh * D_ * M_;

    const int rg   = lane >> 3;
    const int ch   = lane & 7;
    const int skw  = (rg & 3) | ((wid & 1) << 2);   // sK(w*8+rg)
    const int kc   = (ch ^ skw) << 3;
    const int vc   = (ch ^ rg) << 3;                // sV(w*8+rg) = rg
    const int srow = wid * 8 + rg;
    const int ldst = wid * 512;

#define STAGE(BUF, KV0)                                                        \
    gld16(Kp + (size_t)((KV0) + srow) * D_ + kc, &Klds[BUF][ldst]);            \
    gld16(Vp + (size_t)srow * M_ + (KV0) + vc,  &Vlds[BUF][ldst]);

    const int rm0 = ((l15 >> 2) * 8) + (l15 & 3);   // permuted K row (QK^T swap)
    const int sq  = (l15 & 7) << 3;
    const int ak00 = rm0 * 64 + (( 0 + lg * 8) ^ sq);
    const int ak01 = rm0 * 64 + ((32 + lg * 8) ^ sq);
    const int ak10 = ak00 + 256;
    const int ak11 = ak01 + 256;
    const int av0 = l15 * 64 + (( 0 + lg * 8) ^ sq);
    const int av1 = l15 * 64 + ((32 + lg * 8) ^ sq);

    bf16x8 qf0 = *reinterpret_cast<const bf16x8*>(Qp + (size_t)l15 * D_ +      lg * 8);
    bf16x8 qf1 = *reinterpret_cast<const bf16x8*>(Qp + (size_t)l15 * D_ + 32 + lg * 8);

    bf16x8 onesf;
#pragma unroll
    for (int j = 0; j < 8; ++j) onesf[j] = (__bf16)1.0f;

    f32x4 o0 = {}, o1 = {}, o2 = {}, o3 = {}, ors = {};

#define COMPUTE(KB, VB, KOFF, AV)                                                               \
    {                                                                                           \
        bf16x8 k00 = *reinterpret_cast<const bf16x8*>((KB) + ak00 + (KOFF));                    \
        bf16x8 k01 = *reinterpret_cast<const bf16x8*>((KB) + ak01 + (KOFF));                    \
        bf16x8 k10 = *reinterpret_cast<const bf16x8*>((KB) + ak10 + (KOFF));                    \
        bf16x8 k11 = *reinterpret_cast<const bf16x8*>((KB) + ak11 + (KOFF));                    \
        bf16x8 v0  = *reinterpret_cast<const bf16x8*>((VB) + (AV));                             \
        bf16x8 v1  = *reinterpret_cast<const bf16x8*>((VB) + (AV) + 1024);                      \
        bf16x8 v2  = *reinterpret_cast<const bf16x8*>((VB) + (AV) + 2048);                      \
        bf16x8 v3  = *reinterpret_cast<const bf16x8*>((VB) + (AV) + 3072);                      \
        f32x4 s0 = {}, s1 = {};                                                                 \
        s0 = __builtin_amdgcn_mfma_f32_16x16x32_bf16(k00, qf0, s0, 0, 0, 0);                    \
        s0 = __builtin_amdgcn_mfma_f32_16x16x32_bf16(k01, qf1, s0, 0, 0, 0);                    \
        s1 = __builtin_amdgcn_mfma_f32_16x16x32_bf16(k10, qf0, s1, 0, 0, 0);                    \
        s1 = __builtin_amdgcn_mfma_f32_16x16x32_bf16(k11, qf1, s1, 0, 0, 0);                    \
        bf16x8 pf;                                                                              \
        pf[0] = (__bf16)__builtin_amdgcn_exp2f(s0[0]);                                          \
        pf[1] = (__bf16)__builtin_amdgcn_exp2f(s0[1]);                                          \
        pf[2] = (__bf16)__builtin_amdgcn_exp2f(s0[2]);                                          \
        pf[3] = (__bf16)__builtin_amdgcn_exp2f(s0[3]);                                          \
        pf[4] = (__bf16)__builtin_amdgcn_exp2f(s1[0]);                                          \
        pf[5] = (__bf16)__builtin_amdgcn_exp2f(s1[1]);                                          \
        pf[6] = (__bf16)__builtin_amdgcn_exp2f(s1[2]);                                          \
        pf[7] = (__bf16)__builtin_amdgcn_exp2f(s1[3]);                                          \
        ors = __builtin_amdgcn_mfma_f32_16x16x32_bf16(pf, onesf, ors, 0, 0, 0);                 \
        o0 = __builtin_amdgcn_mfma_f32_16x16x32_bf16(pf, v0, o0, 0, 0, 0);                      \
        o1 = __builtin_amdgcn_mfma_f32_16x16x32_bf16(pf, v1, o1, 0, 0, 0);                      \
        o2 = __builtin_amdgcn_mfma_f32_16x16x32_bf16(pf, v2, o2, 0, 0, 0);                      \
        o3 = __builtin_amdgcn_mfma_f32_16x16x32_bf16(pf, v3, o3, 0, 0, 0);                      \
    }

    STAGE(0, 0)
    __syncthreads();

    for (int t = 0; t < 32; t += 2) {
        if (t + 1 < 32) { STAGE(1, (t + 1) * 64) }
        COMPUTE(Klds[0], Vlds[0], 0,    av0)
        COMPUTE(Klds[0], Vlds[0], 2048, av1)
        __syncthreads();
        if (t + 2 < 32) { STAGE(0, (t + 2) * 64) }
        COMPUTE(Klds[1], Vlds[1], 0,    av0)
        COMPUTE(Klds[1], Vlds[1], 2048, av1)
        __syncthreads();
    }
#undef STAGE
#undef COMPUTE

#pragma unroll
    for (int r = 0; r < 4; ++r) {
        float inv = 1.0f / ors[r];
        size_t row = ((size_t)b * N_ + qbase + lg * 4 + r) * QD_ + h * D_ + l15;
        AO[row +  0] = (__bf16)(o0[r] * inv);
        AO[row + 16] = (__bf16)(o1[r] * inv);
        AO[row + 32] = (__bf16)(o2[r] * inv);
        AO[row + 48] = (__bf16)(o3[r] * inv);
    }
}

// ---------------------------------------------------------------------------
extern "C" void kernel_launch(void* const* d_in, const int* in_sizes, int n_in,
                              void* d_out, int out_size, void* d_ws, size_t ws_size,
                              hipStream_t stream) {
    const float* x   = (const float*)d_in[0];
    const float* ctx = (const float*)d_in[1];
    const float* Wq  = (const float*)d_in[2];
    const float* Wk  = (const float*)d_in[3];
    const float* Wv  = (const float*)d_in[4];
    const float* Wo  = (const float*)d_in[5];

    char* ws = (char*)d_ws;
    __bf16* xb  = (__bf16*)(ws);                      // 0-8 MB
    __bf16* cb  = (__bf16*)(ws + (8u  << 20));        // 8-16 MB
    __bf16* Wtq = (__bf16*)(ws + (16u << 20));        // 16-18 MB
    __bf16* Wtk = (__bf16*)(ws + (18u << 20));        // 18-20
    __bf16* Wtv = (__bf16*)(ws + (20u << 20));        // 20-22
    __bf16* Wto = (__bf16*)(ws + (22u << 20));        // 22-24
    __bf16* Qb  = (__bf16*)(ws + (24u << 20));        // 24-32  [bh][2048][64], pre-scaled
    __bf16* Kb  = (__bf16*)(ws + (32u << 20));        // 32-40  [bh][2048][64]
    __bf16* Vt  = (__bf16*)(ws + (40u << 20));        // 40-48  [bh][64][2048]
    __bf16* AO  = (__bf16*)(ws + (48u << 20));        // 48-56  [4096][1024]

    cvt2_f32_bf16<<<dim3(4096, 2), 256, 0, stream>>>(x, ctx, xb, cb);
    transpose4_cvt<<<dim3(16, 16, 4), 256, 0, stream>>>(Wq, Wk, Wv, Wo, Wtq, Wtk, Wtv, Wto);
    gemm_qkv<<<dim3(32, 8, 3), 256, 0, stream>>>(xb, cb, Wtq, Wtk, Wtv, Qb, Kb, Vt);
    attn_kernel<<<512, 512, 0, stream>>>(Qb, Kb, Vt, AO);
    gemm_out<<<dim3(32, 8), 256, 0, stream>>>(AO, Wto, (float*)d_out);
}

// Round 11
// 124.593 us; speedup vs baseline: 1.0160x; 1.0160x over previous
//
#include <hip/hip_runtime.h>
#include <hip/hip_bf16.h>

// ---------------------------------------------------------------------------
// CrossAttention: out = softmax((x Wq)(ctx Wk)^T * scale) (ctx Wv) Wo
// B=2, N=M=2048, H=16, D=64, QD=INNER=1024. fp32 in/out, bf16 MFMA inside.
// R11: GEMMs — R9 stage-ahead schedule, but 128x64 tile (wave 64x32) for
// 6 blocks/CU = 24 waves/CU (TLP doubling; R10 ablation showed the limiter is
// pipeline fill, not sync schedule / conflicts / tile-arithmetic-ratio).
// cvt + weight transposes fused into one `prep` launch. Attention = R7.
// ---------------------------------------------------------------------------

typedef __attribute__((ext_vector_type(8))) __bf16    bf16x8;
typedef __attribute__((ext_vector_type(4))) __bf16    bf16x4;
typedef __attribute__((ext_vector_type(4))) float     f32x4;

#define B_    2
#define H_    16
#define N_    2048
#define M_    2048
#define D_    64
#define QD_   1024

// 0.125 * log2(e): folds softmax scale and exp->exp2 conversion into Q
#define QSCALE 0.18033688011112042f

// direct global->LDS async copy, 16B per lane; LDS dest = wave-uniform base + lane*16
__device__ __forceinline__ void gld16(const __bf16* g, __bf16* l) {
    __builtin_amdgcn_global_load_lds(
        (const __attribute__((address_space(1))) unsigned int*)(g),
        (__attribute__((address_space(3))) unsigned int*)(l), 16, 0, 0);
}

// ---------------------------------------------------------------------------
// prep: z<2 -> f32->bf16 convert of x/ctx; z>=2 -> weight transpose+convert.
// grid (16,16,6), 256 threads.
// ---------------------------------------------------------------------------
__global__ __launch_bounds__(256) void prep(const float* __restrict__ x,
                                            const float* __restrict__ ctx,
                                            const float* __restrict__ w0,
                                            const float* __restrict__ w1,
                                            const float* __restrict__ w2,
                                            const float* __restrict__ w3,
                                            __bf16* __restrict__ xb,
                                            __bf16* __restrict__ cb,
                                            __bf16* __restrict__ t0,
                                            __bf16* __restrict__ t1,
                                            __bf16* __restrict__ t2,
                                            __bf16* __restrict__ t3) {
    __shared__ float tile[64][65];
    const int z = blockIdx.z;
    if (z < 2) {
        const float* src = z ? ctx : x;
        __bf16*      dst = z ? cb  : xb;
        const size_t base = (size_t)(blockIdx.y * 16 + blockIdx.x) * 16384;
#pragma unroll
        for (int p = 0; p < 16; ++p) {
            size_t i = base + p * 1024 + threadIdx.x * 4;
            float4 v = *reinterpret_cast<const float4*>(src + i);
            bf16x4 o;
            o.x = (__bf16)v.x; o.y = (__bf16)v.y; o.z = (__bf16)v.z; o.w = (__bf16)v.w;
            *reinterpret_cast<bf16x4*>(dst + i) = o;
        }
        return;
    }
    const int w = z - 2;
    const float* in = (w == 0) ? w0 : (w == 1) ? w1 : (w == 2) ? w2 : w3;
    __bf16*     out = (w == 0) ? t0 : (w == 1) ? t1 : (w == 2) ? t2 : t3;
    const int i0 = blockIdx.x * 64;
    const int o0 = blockIdx.y * 64;
    const int t  = threadIdx.x;
    const int r  = t >> 4;
    const int c4 = (t & 15) * 4;
#pragma unroll
    for (int p = 0; p < 4; ++p) {
        int row = p * 16 + r;
        float4 v = *reinterpret_cast<const float4*>(in + (size_t)(i0 + row) * QD_ + o0 + c4);
        tile[row][c4 + 0] = v.x; tile[row][c4 + 1] = v.y;
        tile[row][c4 + 2] = v.z; tile[row][c4 + 3] = v.w;
    }
    __syncthreads();
#pragma unroll
    for (int p = 0; p < 4; ++p) {
        int orow = p * 16 + r;
        bf16x4 o;
        o.x = (__bf16)tile[c4 + 0][orow];
        o.y = (__bf16)tile[c4 + 1][orow];
        o.z = (__bf16)tile[c4 + 2][orow];
        o.w = (__bf16)tile[c4 + 3][orow];
        *reinterpret_cast<bf16x4*>(out + (size_t)(o0 + orow) * QD_ + i0 + c4) = o;
    }
}

// ---------------------------------------------------------------------------
// GEMM core R11: 128x64 tile, 4 waves (2x2), wave = 64x32 (4x2 frags), BK=32.
// A[128x32]+B[64x32] staged via gld16 (stage-ahead dbuf, one barrier/K-step),
// XOR granule swizzle both operands (pre-swizzled source + swizzled ds_read).
// LDS 24 KB -> 6 blocks/CU. 3 gld16 per wave per step.
// ---------------------------------------------------------------------------
#define GEMM_BODY(A_, Bt_)                                                                     \
    __shared__ __align__(16) __bf16 Alds[2][128 * 32];                                         \
    __shared__ __align__(16) __bf16 Blds[2][64 * 32];                                          \
    const int tid  = threadIdx.x;                                                              \
    const int wid  = tid >> 6;                                                                 \
    const int lane = tid & 63;                                                                 \
    const int l15  = lane & 15;                                                                \
    const int lg   = lane >> 4;                                                                \
    const int wr   = wid >> 1;                                                                 \
    const int wc   = wid & 1;                                                                  \
    const int rowBase = blockIdx.x * 128;                                                      \
    const int colBase = blockIdx.y * 64;                                                       \
    const int srowA = wid * 32 + (lane >> 2);                                                  \
    const int srowB = wid * 16 + (lane >> 2);                                                  \
    const int sgA   = ((lane & 3) ^ ((srowA >> 1) & 3)) * 8;                                   \
    const int sgB   = ((lane & 3) ^ ((srowB >> 1) & 3)) * 8;                                   \
    const __bf16* Ag  = A_  + (size_t)(rowBase + srowA) * QD_ + sgA;                           \
    const __bf16* Ag2 = Ag  + (size_t)16 * QD_;  /* same swizzle: +16 keeps (row>>1)&3 */      \
    const __bf16* Bg  = Bt_ + (size_t)(colBase + srowB) * QD_ + sgB;                           \
    const int sOffA  = (wid * 32) * 32;                                                        \
    const int sOffA2 = sOffA + 16 * 32;                                                        \
    const int sOffB  = (wid * 16) * 32;                                                        \
    int aoff[4], boff[2];                                                                      \
    _Pragma("unroll")                                                                          \
    for (int m = 0; m < 4; ++m) {                                                              \
        int ra = wr * 64 + m * 16 + l15;                                                       \
        aoff[m] = ra * 32 + ((lg ^ ((ra >> 1) & 3)) * 8);                                      \
    }                                                                                          \
    _Pragma("unroll")                                                                          \
    for (int n = 0; n < 2; ++n) {                                                              \
        int rb = wc * 32 + n * 16 + l15;                                                       \
        boff[n] = rb * 32 + ((lg ^ ((rb >> 1) & 3)) * 8);                                      \
    }                                                                                          \
    f32x4 acc[4][2] = {};                                                                      \
    gld16(Ag,  &Alds[0][sOffA]);                                                               \
    gld16(Ag2, &Alds[0][sOffA2]);                                                              \
    gld16(Bg,  &Blds[0][sOffB]);                                                               \
    __syncthreads();                                                                           \
    for (int t = 0; t < 32; t += 2) {                                                          \
        if (t + 1 < 32) {                                                                      \
            int kn = (t + 1) * 32;                                                             \
            gld16(Ag + kn,  &Alds[1][sOffA]);                                                  \
            gld16(Ag2 + kn, &Alds[1][sOffA2]);                                                 \
            gld16(Bg + kn,  &Blds[1][sOffB]);                                                  \
        }                                                                                      \
        GCOMPUTE(0)                                                                            \
        __syncthreads();                                                                       \
        if (t + 2 < 32) {                                                                      \
            int kn = (t + 2) * 32;                                                             \
            gld16(Ag + kn,  &Alds[0][sOffA]);                                                  \
            gld16(Ag2 + kn, &Alds[0][sOffA2]);                                                 \
            gld16(Bg + kn,  &Blds[0][sOffB]);                                                  \
        }                                                                                      \
        GCOMPUTE(1)                                                                            \
        __syncthreads();                                                                       \
    }

#define GCOMPUTE(BUF)                                                                          \
    {                                                                                          \
        bf16x8 a[4], b[2];                                                                     \
        _Pragma("unroll")                                                                      \
        for (int m = 0; m < 4; ++m)                                                            \
            a[m] = *reinterpret_cast<const bf16x8*>(&Alds[BUF][aoff[m]]);                      \
        _Pragma("unroll")                                                                      \
        for (int n = 0; n < 2; ++n)                                                            \
            b[n] = *reinterpret_cast<const bf16x8*>(&Blds[BUF][boff[n]]);                      \
        _Pragma("unroll")                                                                      \
        for (int m = 0; m < 4; ++m)                                                            \
            _Pragma("unroll")                                                                  \
            for (int n = 0; n < 2; ++n)                                                        \
                acc[m][n] = __builtin_amdgcn_mfma_f32_16x16x32_bf16(a[m], b[n], acc[m][n], 0, 0, 0); \
    }

// fused Q/K/V projection: blockIdx.z selects {Q (scaled), K, V^T} output
__global__ __launch_bounds__(256) void gemm_qkv(const __bf16* __restrict__ xb,
                                                const __bf16* __restrict__ cb,
                                                const __bf16* __restrict__ Wtq,
                                                const __bf16* __restrict__ Wtk,
                                                const __bf16* __restrict__ Wtv,
                                                __bf16* __restrict__ Qb,
                                                __bf16* __restrict__ Kb,
                                                __bf16* __restrict__ Vt) {
    const int z = blockIdx.z;
    const __bf16* Asel = (z == 0) ? xb : cb;
    const __bf16* Bsel = (z == 0) ? Wtq : (z == 1) ? Wtk : Wtv;
    GEMM_BODY(Asel, Bsel)
#pragma unroll
    for (int m = 0; m < 4; ++m)
#pragma unroll
        for (int n = 0; n < 2; ++n)
#pragma unroll
            for (int r = 0; r < 4; ++r) {
                int rr = rowBase + wr * 64 + m * 16 + lg * 4 + r;
                int cc = colBase + wc * 32 + n * 16 + l15;
                float v = acc[m][n][r];
                int b_ = rr >> 11, nn = rr & 2047, hh = cc >> 6, dd = cc & 63;
                if (z == 0) {
                    Qb[((size_t)(b_ * H_ + hh) * N_ + nn) * D_ + dd] = (__bf16)(v * QSCALE);
                } else if (z == 1) {
                    Kb[((size_t)(b_ * H_ + hh) * N_ + nn) * D_ + dd] = (__bf16)v;
                } else {
                    Vt[((size_t)(b_ * H_ + hh) * D_ + dd) * M_ + nn] = (__bf16)v;
                }
            }
}

// final projection: AO @ Wto -> f32 out
__global__ __launch_bounds__(256) void gemm_out(const __bf16* __restrict__ AO,
                                                const __bf16* __restrict__ Wto,
                                                float* __restrict__ out) {
    GEMM_BODY(AO, Wto)
#pragma unroll
    for (int m = 0; m < 4; ++m)
#pragma unroll
        for (int n = 0; n < 2; ++n)
#pragma unroll
            for (int r = 0; r < 4; ++r) {
                int rr = rowBase + wr * 64 + m * 16 + lg * 4 + r;
                int cc = colBase + wc * 32 + n * 16 + l15;
                out[(size_t)rr * QD_ + cc] = acc[m][n][r];
            }
}

// ---------------------------------------------------------------------------
// Attention (R7, unchanged). Grid 512 (XCD-swizzled), 8 waves x 16 q-rows,
// K/V LDS dbuf (32 KB), XOR swizzle via pre-swizzled global source, swapped
// QK^T -> P lane-local, row-sums via ones-MFMA, exp2 with pre-scaled Q.
// ---------------------------------------------------------------------------
__global__ __launch_bounds__(512, 4) void attn_kernel(const __bf16* __restrict__ Q,
                                                      const __bf16* __restrict__ K,
                                                      const __bf16* __restrict__ Vt,
                                                      __bf16* __restrict__ AO) {
    __shared__ __align__(16) __bf16 Klds[2][4096];
    __shared__ __align__(16) __bf16 Vlds[2][4096];

    const int logical = (blockIdx.x & 7) * 64 + (blockIdx.x >> 3);
    const int qt   = logical & 15;
    const int bh   = logical >> 4;
    const int b    = bh >> 4;
    const int h    = bh & 15;
    const int wid  = threadIdx.x >> 6;     // 0..7
    const int lane = threadIdx.x & 63;
    const int l15  = lane & 15;
    const int lg   = lane >> 4;
    const int qbase = qt * 128 + wid * 16;

    const __bf16* Qp = Q  + ((size_t)bh * N_ + qbase) * D_;
    const __bf16* Kp = K  + (size_t)bh * M_ * D_;
    const __bf16* Vp = Vt + (size_t)bh * D_ * M_;

    const int rg   = lane >> 3;
    const int ch   = lane & 7;
    const int skw  = (rg & 3) | ((wid & 1) << 2);   // sK(w*8+rg)
    const int kc   = (ch ^ skw) << 3;
    const int vc   = (ch ^ rg) << 3;                // sV(w*8+rg) = rg
    const int srow = wid * 8 + rg;
    const int ldst = wid * 512;

#define STAGE(BUF, KV0)                                                        \
    gld16(Kp + (size_t)((KV0) + srow) * D_ + kc, &Klds[BUF][ldst]);            \
    gld16(Vp + (size_t)srow * M_ + (KV0) + vc,  &Vlds[BUF][ldst]);

    const int rm0 = ((l15 >> 2) * 8) + (l15 & 3);   // permuted K row (QK^T swap)
    const int sq  = (l15 & 7) << 3;
    const int ak00 = rm0 * 64 + (( 0 + lg * 8) ^ sq);
    const int ak01 = rm0 * 64 + ((32 + lg * 8) ^ sq);
    const int ak10 = ak00 + 256;
    const int ak11 = ak01 + 256;
    const int av0 = l15 * 64 + (( 0 + lg * 8) ^ sq);
    const int av1 = l15 * 64 + ((32 + lg * 8) ^ sq);

    bf16x8 qf0 = *reinterpret_cast<const bf16x8*>(Qp + (size_t)l15 * D_ +      lg * 8);
    bf16x8 qf1 = *reinterpret_cast<const bf16x8*>(Qp + (size_t)l15 * D_ + 32 + lg * 8);

    bf16x8 onesf;
#pragma unroll
    for (int j = 0; j < 8; ++j) onesf[j] = (__bf16)1.0f;

    f32x4 o0 = {}, o1 = {}, o2 = {}, o3 = {}, ors = {};

#define COMPUTE(KB, VB, KOFF, AV)                                                               \
    {                                                                                           \
        bf16x8 k00 = *reinterpret_cast<const bf16x8*>((KB) + ak00 + (KOFF));                    \
        bf16x8 k01 = *reinterpret_cast<const bf16x8*>((KB) + ak01 + (KOFF));                    \
        bf16x8 k10 = *reinterpret_cast<const bf16x8*>((KB) + ak10 + (KOFF));                    \
        bf16x8 k11 = *reinterpret_cast<const bf16x8*>((KB) + ak11 + (KOFF));                    \
        bf16x8 v0  = *reinterpret_cast<const bf16x8*>((VB) + (AV));                             \
        bf16x8 v1  = *reinterpret_cast<const bf16x8*>((VB) + (AV) + 1024);                      \
        bf16x8 v2  = *reinterpret_cast<const bf16x8*>((VB) + (AV) + 2048);                      \
        bf16x8 v3  = *reinterpret_cast<const bf16x8*>((VB) + (AV) + 3072);                      \
        f32x4 s0 = {}, s1 = {};                                                                 \
        s0 = __builtin_amdgcn_mfma_f32_16x16x32_bf16(k00, qf0, s0, 0, 0, 0);                    \
        s0 = __builtin_amdgcn_mfma_f32_16x16x32_bf16(k01, qf1, s0, 0, 0, 0);                    \
        s1 = __builtin_amdgcn_mfma_f32_16x16x32_bf16(k10, qf0, s1, 0, 0, 0);                    \
        s1 = __builtin_amdgcn_mfma_f32_16x16x32_bf16(k11, qf1, s1, 0, 0, 0);                    \
        bf16x8 pf;                                                                              \
        pf[0] = (__bf16)__builtin_amdgcn_exp2f(s0[0]);                                          \
        pf[1] = (__bf16)__builtin_amdgcn_exp2f(s0[1]);                                          \
        pf[2] = (__bf16)__builtin_amdgcn_exp2f(s0[2]);                                          \
        pf[3] = (__bf16)__builtin_amdgcn_exp2f(s0[3]);                                          \
        pf[4] = (__bf16)__builtin_amdgcn_exp2f(s1[0]);                                          \
        pf[5] = (__bf16)__builtin_amdgcn_exp2f(s1[1]);                                          \
        pf[6] = (__bf16)__builtin_amdgcn_exp2f(s1[2]);                                          \
        pf[7] = (__bf16)__builtin_amdgcn_exp2f(s1[3]);                                          \
        ors = __builtin_amdgcn_mfma_f32_16x16x32_bf16(pf, onesf, ors, 0, 0, 0);                 \
        o0 = __builtin_amdgcn_mfma_f32_16x16x32_bf16(pf, v0, o0, 0, 0, 0);                      \
        o1 = __builtin_amdgcn_mfma_f32_16x16x32_bf16(pf, v1, o1, 0, 0, 0);                      \
        o2 = __builtin_amdgcn_mfma_f32_16x16x32_bf16(pf, v2, o2, 0, 0, 0);                      \
        o3 = __builtin_amdgcn_mfma_f32_16x16x32_bf16(pf, v3, o3, 0, 0, 0);                      \
    }

    STAGE(0, 0)
    __syncthreads();

    for (int t = 0; t < 32; t += 2) {
        if (t + 1 < 32) { STAGE(1, (t + 1) * 64) }
        COMPUTE(Klds[0], Vlds[0], 0,    av0)
        COMPUTE(Klds[0], Vlds[0], 2048, av1)
        __syncthreads();
        if (t + 2 < 32) { STAGE(0, (t + 2) * 64) }
        COMPUTE(Klds[1], Vlds[1], 0,    av0)
        COMPUTE(Klds[1], Vlds[1], 2048, av1)
        __syncthreads();
    }
#undef STAGE
#undef COMPUTE

#pragma unroll
    for (int r = 0; r < 4; ++r) {
        float inv = 1.0f / ors[r];
        size_t row = ((size_t)b * N_ + qbase + lg * 4 + r) * QD_ + h * D_ + l15;
        AO[row +  0] = (__bf16)(o0[r] * inv);
        AO[row + 16] = (__bf16)(o1[r] * inv);
        AO[row + 32] = (__bf16)(o2[r] * inv);
        AO[row + 48] = (__bf16)(o3[r] * inv);
    }
}

// ---------------------------------------------------------------------------
extern "C" void kernel_launch(void* const* d_in, const int* in_sizes, int n_in,
                              void* d_out, int out_size, void* d_ws, size_t ws_size,
                              hipStream_t stream) {
    const float* x   = (const float*)d_in[0];
    const float* ctx = (const float*)d_in[1];
    const float* Wq  = (const float*)d_in[2];
    const float* Wk  = (const float*)d_in[3];
    const float* Wv  = (const float*)d_in[4];
    const float* Wo  = (const float*)d_in[5];

    char* ws = (char*)d_ws;
    __bf16* xb  = (__bf16*)(ws);                      // 0-8 MB
    __bf16* cb  = (__bf16*)(ws + (8u  << 20));        // 8-16 MB
    __bf16* Wtq = (__bf16*)(ws + (16u << 20));        // 16-18 MB
    __bf16* Wtk = (__bf16*)(ws + (18u << 20));        // 18-20
    __bf16* Wtv = (__bf16*)(ws + (20u << 20));        // 20-22
    __bf16* Wto = (__bf16*)(ws + (22u << 20));        // 22-24
    __bf16* Qb  = (__bf16*)(ws + (24u << 20));        // 24-32  [bh][2048][64], pre-scaled
    __bf16* Kb  = (__bf16*)(ws + (32u << 20));        // 32-40  [bh][2048][64]
    __bf16* Vt  = (__bf16*)(ws + (40u << 20));        // 40-48  [bh][64][2048]
    __bf16* AO  = (__bf16*)(ws + (48u << 20));        // 48-56  [4096][1024]

    prep<<<dim3(16, 16, 6), 256, 0, stream>>>(x, ctx, Wq, Wk, Wv, Wo,
                                              xb, cb, Wtq, Wtk, Wtv, Wto);
    gemm_qkv<<<dim3(32, 16, 3), 256, 0, stream>>>(xb, cb, Wtq, Wtk, Wtv, Qb, Kb, Vt);
    attn_kernel<<<512, 512, 0, stream>>>(Qb, Kb, Vt, AO);
    gemm_out<<<dim3(32, 16), 256, 0, stream>>>(AO, Wto, (float*)d_out);
}

// Round 12
// 109.095 us; speedup vs baseline: 1.1603x; 1.1421x over previous
//
#include <hip/hip_runtime.h>
#include <hip/hip_bf16.h>

// ---------------------------------------------------------------------------
// CrossAttention: out = softmax((x Wq)(ctx Wk)^T * scale) (ctx Wv) Wo
// B=2, N=M=2048, H=16, D=64, QD=INNER=1024. fp32 in/out, bf16 MFMA inside.
// R12: GEMMs revert to R9 body (proven best); NEW vectorized epilogue:
// accs repacked through a 32KB LDS pool (V repacked TRANSPOSED) then stored
// with coalesced 16B vector stores — replaces 32 scalar 2B stores/thread
// (V's were 4KB-stride scatter). gemm_out = 128x64 (TLP) + f32 repack.
// Attention unchanged from R7.
// ---------------------------------------------------------------------------

typedef __attribute__((ext_vector_type(8))) __bf16    bf16x8;
typedef __attribute__((ext_vector_type(4))) __bf16    bf16x4;
typedef __attribute__((ext_vector_type(4))) float     f32x4;

#define B_    2
#define H_    16
#define N_    2048
#define M_    2048
#define D_    64
#define QD_   1024

// 0.125 * log2(e): folds softmax scale and exp->exp2 conversion into Q
#define QSCALE 0.18033688011112042f

// direct global->LDS async copy, 16B per lane; LDS dest = wave-uniform base + lane*16
__device__ __forceinline__ void gld16(const __bf16* g, __bf16* l) {
    __builtin_amdgcn_global_load_lds(
        (const __attribute__((address_space(1))) unsigned int*)(g),
        (__attribute__((address_space(3))) unsigned int*)(l), 16, 0, 0);
}

// ---------------------------------------------------------------------------
// prep: z<2 -> f32->bf16 convert of x/ctx; z>=2 -> weight transpose+convert.
// ---------------------------------------------------------------------------
__global__ __launch_bounds__(256) void prep(const float* __restrict__ x,
                                            const float* __restrict__ ctx,
                                            const float* __restrict__ w0,
                                            const float* __restrict__ w1,
                                            const float* __restrict__ w2,
                                            const float* __restrict__ w3,
                                            __bf16* __restrict__ xb,
                                            __bf16* __restrict__ cb,
                                            __bf16* __restrict__ t0,
                                            __bf16* __restrict__ t1,
                                            __bf16* __restrict__ t2,
                                            __bf16* __restrict__ t3) {
    __shared__ float tile[64][65];
    const int z = blockIdx.z;
    if (z < 2) {
        const float* src = z ? ctx : x;
        __bf16*      dst = z ? cb  : xb;
        const size_t base = (size_t)(blockIdx.y * 16 + blockIdx.x) * 16384;
#pragma unroll
        for (int p = 0; p < 16; ++p) {
            size_t i = base + p * 1024 + threadIdx.x * 4;
            float4 v = *reinterpret_cast<const float4*>(src + i);
            bf16x4 o;
            o.x = (__bf16)v.x; o.y = (__bf16)v.y; o.z = (__bf16)v.z; o.w = (__bf16)v.w;
            *reinterpret_cast<bf16x4*>(dst + i) = o;
        }
        return;
    }
    const int w = z - 2;
    const float* in = (w == 0) ? w0 : (w == 1) ? w1 : (w == 2) ? w2 : w3;
    __bf16*     out = (w == 0) ? t0 : (w == 1) ? t1 : (w == 2) ? t2 : t3;
    const int i0 = blockIdx.x * 64;
    const int o0 = blockIdx.y * 64;
    const int t  = threadIdx.x;
    const int r  = t >> 4;
    const int c4 = (t & 15) * 4;
#pragma unroll
    for (int p = 0; p < 4; ++p) {
        int row = p * 16 + r;
        float4 v = *reinterpret_cast<const float4*>(in + (size_t)(i0 + row) * QD_ + o0 + c4);
        tile[row][c4 + 0] = v.x; tile[row][c4 + 1] = v.y;
        tile[row][c4 + 2] = v.z; tile[row][c4 + 3] = v.w;
    }
    __syncthreads();
#pragma unroll
    for (int p = 0; p < 4; ++p) {
        int orow = p * 16 + r;
        bf16x4 o;
        o.x = (__bf16)tile[c4 + 0][orow];
        o.y = (__bf16)tile[c4 + 1][orow];
        o.z = (__bf16)tile[c4 + 2][orow];
        o.w = (__bf16)tile[c4 + 3][orow];
        *reinterpret_cast<bf16x4*>(out + (size_t)(o0 + orow) * QD_ + i0 + c4) = o;
    }
}

// ---------------------------------------------------------------------------
// gemm_qkv R12: R9 body (128x128 tile, 4 waves 2x2, wave 64x64, BK=32,
// stage-ahead dbuf via gld16, XOR granule swizzle both operands), with the
// 32KB LDS carved from one POOL so the epilogue can reuse it for repack.
// Epilogue: acc -> POOL (V transposed) -> coalesced bf16x8 stores.
// ---------------------------------------------------------------------------
__global__ __launch_bounds__(256) void gemm_qkv(const __bf16* __restrict__ xb,
                                                const __bf16* __restrict__ cb,
                                                const __bf16* __restrict__ Wtq,
                                                const __bf16* __restrict__ Wtk,
                                                const __bf16* __restrict__ Wtv,
                                                __bf16* __restrict__ Qb,
                                                __bf16* __restrict__ Kb,
                                                __bf16* __restrict__ Vt) {
    __shared__ __align__(16) __bf16 POOL[16384];   // 32 KB
    __bf16* const Al0 = POOL;
    __bf16* const Al1 = POOL + 4096;
    __bf16* const Bl0 = POOL + 8192;
    __bf16* const Bl1 = POOL + 12288;

    const int z = blockIdx.z;
    const __bf16* A_  = (z == 0) ? xb : cb;
    const __bf16* Bt_ = (z == 0) ? Wtq : (z == 1) ? Wtk : Wtv;

    const int tid  = threadIdx.x;
    const int wid  = tid >> 6;
    const int lane = tid & 63;
    const int l15  = lane & 15;
    const int lg   = lane >> 4;
    const int wr   = wid >> 1;
    const int wc   = wid & 1;
    const int rowBase = blockIdx.x * 128;
    const int colBase = blockIdx.y * 128;
    const int srow = wid * 32 + (lane >> 2);
    const int sg   = ((lane & 3) ^ ((srow >> 1) & 3)) * 8;  // pre-swizzled src granule
    const __bf16* Ag  = A_  + (size_t)(rowBase + srow) * QD_ + sg;
    const __bf16* Ag2 = Ag  + (size_t)16 * QD_;
    const __bf16* Bg  = Bt_ + (size_t)(colBase + srow) * QD_ + sg;
    const __bf16* Bg2 = Bg  + (size_t)16 * QD_;
    const int sOff  = (wid * 32) * 32;
    const int sOff2 = sOff + 16 * 32;
    int aoff[4], boff[4];
#pragma unroll
    for (int m = 0; m < 4; ++m) {
        int ra = wr * 64 + m * 16 + l15;
        int rb = wc * 64 + m * 16 + l15;
        aoff[m] = ra * 32 + ((lg ^ ((ra >> 1) & 3)) * 8);
        boff[m] = rb * 32 + ((lg ^ ((rb >> 1) & 3)) * 8);
    }
    f32x4 acc[4][4] = {};

#define GCOMPUTE(AL, BL)                                                                       \
    {                                                                                          \
        bf16x8 a[4], b[4];                                                                     \
        _Pragma("unroll")                                                                      \
        for (int m = 0; m < 4; ++m)                                                            \
            a[m] = *reinterpret_cast<const bf16x8*>(&(AL)[aoff[m]]);                           \
        _Pragma("unroll")                                                                      \
        for (int n = 0; n < 4; ++n)                                                            \
            b[n] = *reinterpret_cast<const bf16x8*>(&(BL)[boff[n]]);                           \
        _Pragma("unroll")                                                                      \
        for (int m = 0; m < 4; ++m)                                                            \
            _Pragma("unroll")                                                                  \
            for (int n = 0; n < 4; ++n)                                                        \
                acc[m][n] = __builtin_amdgcn_mfma_f32_16x16x32_bf16(a[m], b[n], acc[m][n], 0, 0, 0); \
    }

    gld16(Ag,  Al0 + sOff);
    gld16(Ag2, Al0 + sOff2);
    gld16(Bg,  Bl0 + sOff);
    gld16(Bg2, Bl0 + sOff2);
    __syncthreads();
    for (int t = 0; t < 32; t += 2) {
        if (t + 1 < 32) {
            int kn = (t + 1) * 32;
            gld16(Ag + kn,  Al1 + sOff);
            gld16(Ag2 + kn, Al1 + sOff2);
            gld16(Bg + kn,  Bl1 + sOff);
            gld16(Bg2 + kn, Bl1 + sOff2);
        }
        GCOMPUTE(Al0, Bl0)
        __syncthreads();
        if (t + 2 < 32) {
            int kn = (t + 2) * 32;
            gld16(Ag + kn,  Al0 + sOff);
            gld16(Ag2 + kn, Al0 + sOff2);
            gld16(Bg + kn,  Bl0 + sOff);
            gld16(Bg2 + kn, Bl0 + sOff2);
        }
        GCOMPUTE(Al1, Bl1)
        __syncthreads();
    }
#undef GCOMPUTE

    // ---- epilogue: repack into POOL (V transposed), then coalesced stores ----
#pragma unroll
    for (int m = 0; m < 4; ++m)
#pragma unroll
        for (int n = 0; n < 4; ++n)
#pragma unroll
            for (int r = 0; r < 4; ++r) {
                float v = acc[m][n][r];
                if (z == 0) v *= QSCALE;
                int rl = wr * 64 + m * 16 + lg * 4 + r;
                int cl = wc * 64 + n * 16 + l15;
                if (z == 2) POOL[cl * 128 + rl] = (__bf16)v;   // [d-col][token]
                else        POOL[rl * 128 + cl] = (__bf16)v;   // [token][d-col]
            }
    __syncthreads();

    const int prow0 = tid >> 4;         // 0..15
    const int pcol  = (tid & 15) * 8;   // 0..120
#pragma unroll
    for (int s = 0; s < 8; ++s) {
        int row = s * 16 + prow0;
        bf16x8 vv = *reinterpret_cast<const bf16x8*>(&POOL[row * 128 + pcol]);
        if (z == 2) {
            int cc = colBase + row, rr = rowBase + pcol;
            int b_ = rr >> 11, mm = rr & 2047, hh = cc >> 6, dd = cc & 63;
            *reinterpret_cast<bf16x8*>(&Vt[((size_t)(b_ * H_ + hh) * D_ + dd) * M_ + mm]) = vv;
        } else {
            int rr = rowBase + row, cc = colBase + pcol;
            int b_ = rr >> 11, nn = rr & 2047, hh = cc >> 6, dd = cc & 63;
            __bf16* dst = (z == 0) ? Qb : Kb;
            *reinterpret_cast<bf16x8*>(&dst[((size_t)(b_ * H_ + hh) * N_ + nn) * D_ + dd]) = vv;
        }
    }
}

// ---------------------------------------------------------------------------
// gemm_out R12: 128x64 tile (R11 geometry, 512 blocks for TLP), stage-ahead
// dbuf + swizzle, f32 repack epilogue -> coalesced float4 stores.
// ---------------------------------------------------------------------------
__global__ __launch_bounds__(256) void gemm_out(const __bf16* __restrict__ AO,
                                                const __bf16* __restrict__ Wto,
                                                float* __restrict__ out) {
    __shared__ __align__(16) __bf16 POOL[16384];   // 32 KB
    __bf16* const Al0 = POOL;
    __bf16* const Al1 = POOL + 4096;
    __bf16* const Bl0 = POOL + 8192;
    __bf16* const Bl1 = POOL + 10240;

    const int tid  = threadIdx.x;
    const int wid  = tid >> 6;
    const int lane = tid & 63;
    const int l15  = lane & 15;
    const int lg   = lane >> 4;
    const int wr   = wid >> 1;
    const int wc   = wid & 1;
    const int rowBase = blockIdx.x * 128;
    const int colBase = blockIdx.y * 64;
    const int srowA = wid * 32 + (lane >> 2);
    const int srowB = wid * 16 + (lane >> 2);
    const int sgA   = ((lane & 3) ^ ((srowA >> 1) & 3)) * 8;
    const int sgB   = ((lane & 3) ^ ((srowB >> 1) & 3)) * 8;
    const __bf16* Ag  = AO  + (size_t)(rowBase + srowA) * QD_ + sgA;
    const __bf16* Ag2 = Ag  + (size_t)16 * QD_;
    const __bf16* Bg  = Wto + (size_t)(colBase + srowB) * QD_ + sgB;
    const int sOffA  = (wid * 32) * 32;
    const int sOffA2 = sOffA + 16 * 32;
    const int sOffB  = (wid * 16) * 32;
    int aoff[4], boff[2];
#pragma unroll
    for (int m = 0; m < 4; ++m) {
        int ra = wr * 64 + m * 16 + l15;
        aoff[m] = ra * 32 + ((lg ^ ((ra >> 1) & 3)) * 8);
    }
#pragma unroll
    for (int n = 0; n < 2; ++n) {
        int rb = wc * 32 + n * 16 + l15;
        boff[n] = rb * 32 + ((lg ^ ((rb >> 1) & 3)) * 8);
    }
    f32x4 acc[4][2] = {};

#define GCOMPUTE2(AL, BL)                                                                      \
    {                                                                                          \
        bf16x8 a[4], b[2];                                                                     \
        _Pragma("unroll")                                                                      \
        for (int m = 0; m < 4; ++m)                                                            \
            a[m] = *reinterpret_cast<const bf16x8*>(&(AL)[aoff[m]]);                           \
        _Pragma("unroll")                                                                      \
        for (int n = 0; n < 2; ++n)                                                            \
            b[n] = *reinterpret_cast<const bf16x8*>(&(BL)[boff[n]]);                           \
        _Pragma("unroll")                                                                      \
        for (int m = 0; m < 4; ++m)                                                            \
            _Pragma("unroll")                                                                  \
            for (int n = 0; n < 2; ++n)                                                        \
                acc[m][n] = __builtin_amdgcn_mfma_f32_16x16x32_bf16(a[m], b[n], acc[m][n], 0, 0, 0); \
    }

    gld16(Ag,  Al0 + sOffA);
    gld16(Ag2, Al0 + sOffA2);
    gld16(Bg,  Bl0 + sOffB);
    __syncthreads();
    for (int t = 0; t < 32; t += 2) {
        if (t + 1 < 32) {
            int kn = (t + 1) * 32;
            gld16(Ag + kn,  Al1 + sOffA);
            gld16(Ag2 + kn, Al1 + sOffA2);
            gld16(Bg + kn,  Bl1 + sOffB);
        }
        GCOMPUTE2(Al0, Bl0)
        __syncthreads();
        if (t + 2 < 32) {
            int kn = (t + 2) * 32;
            gld16(Ag + kn,  Al0 + sOffA);
            gld16(Ag2 + kn, Al0 + sOffA2);
            gld16(Bg + kn,  Bl0 + sOffB);
        }
        GCOMPUTE2(Al1, Bl1)
        __syncthreads();
    }
#undef GCOMPUTE2

    // f32 repack: POOL aliased as float[128][64]
    float* FP = reinterpret_cast<float*>(POOL);
#pragma unroll
    for (int m = 0; m < 4; ++m)
#pragma unroll
        for (int n = 0; n < 2; ++n)
#pragma unroll
            for (int r = 0; r < 4; ++r) {
                int rl = wr * 64 + m * 16 + lg * 4 + r;
                int cl = wc * 32 + n * 16 + l15;
                FP[rl * 64 + cl] = acc[m][n][r];
            }
    __syncthreads();
    const int prow0 = tid >> 4;
    const int pcol4 = (tid & 15) * 4;
#pragma unroll
    for (int s = 0; s < 8; ++s) {
        int row = s * 16 + prow0;
        float4 vv = *reinterpret_cast<const float4*>(&FP[row * 64 + pcol4]);
        *reinterpret_cast<float4*>(&out[(size_t)(rowBase + row) * QD_ + colBase + pcol4]) = vv;
    }
}

// ---------------------------------------------------------------------------
// Attention (R7, unchanged). Grid 512 (XCD-swizzled), 8 waves x 16 q-rows,
// K/V LDS dbuf (32 KB), XOR swizzle via pre-swizzled global source, swapped
// QK^T -> P lane-local, row-sums via ones-MFMA, exp2 with pre-scaled Q.
// ---------------------------------------------------------------------------
__global__ __launch_bounds__(512, 4) void attn_kernel(const __bf16* __restrict__ Q,
                                                      const __bf16* __restrict__ K,
                                                      const __bf16* __restrict__ Vt,
                                                      __bf16* __restrict__ AO) {
    __shared__ __align__(16) __bf16 Klds[2][4096];
    __shared__ __align__(16) __bf16 Vlds[2][4096];

    const int logical = (blockIdx.x & 7) * 64 + (blockIdx.x >> 3);
    const int qt   = logical & 15;
    const int bh   = logical >> 4;
    const int b    = bh >> 4;
    const int h    = bh & 15;
    const int wid  = threadIdx.x >> 6;     // 0..7
    const int lane = threadIdx.x & 63;
    const int l15  = lane & 15;
    const int lg   = lane >> 4;
    const int qbase = qt * 128 + wid * 16;

    const __bf16* Qp = Q  + ((size_t)bh * N_ + qbase) * D_;
    const __bf16* Kp = K  + (size_t)bh * M_ * D_;
    const __bf16* Vp = Vt + (size_t)bh * D_ * M_;

    const int rg   = lane >> 3;
    const int ch   = lane & 7;
    const int skw  = (rg & 3) | ((wid & 1) << 2);   // sK(w*8+rg)
    const int kc   = (ch ^ skw) << 3;
    const int vc   = (ch ^ rg) << 3;                // sV(w*8+rg) = rg
    const int srow = wid * 8 + rg;
    const int ldst = wid * 512;

#define STAGE(BUF, KV0)                                                        \
    gld16(Kp + (size_t)((KV0) + srow) * D_ + kc, &Klds[BUF][ldst]);            \
    gld16(Vp + (size_t)srow * M_ + (KV0) + vc,  &Vlds[BUF][ldst]);

    const int rm0 = ((l15 >> 2) * 8) + (l15 & 3);   // permuted K row (QK^T swap)
    const int sq  = (l15 & 7) << 3;
    const int ak00 = rm0 * 64 + (( 0 + lg * 8) ^ sq);
    const int ak01 = rm0 * 64 + ((32 + lg * 8) ^ sq);
    const int ak10 = ak00 + 256;
    const int ak11 = ak01 + 256;
    const int av0 = l15 * 64 + (( 0 + lg * 8) ^ sq);
    const int av1 = l15 * 64 + ((32 + lg * 8) ^ sq);

    bf16x8 qf0 = *reinterpret_cast<const bf16x8*>(Qp + (size_t)l15 * D_ +      lg * 8);
    bf16x8 qf1 = *reinterpret_cast<const bf16x8*>(Qp + (size_t)l15 * D_ + 32 + lg * 8);

    bf16x8 onesf;
#pragma unroll
    for (int j = 0; j < 8; ++j) onesf[j] = (__bf16)1.0f;

    f32x4 o0 = {}, o1 = {}, o2 = {}, o3 = {}, ors = {};

#define COMPUTE(KB, VB, KOFF, AV)                                                               \
    {                                                                                           \
        bf16x8 k00 = *reinterpret_cast<const bf16x8*>((KB) + ak00 + (KOFF));                    \
        bf16x8 k01 = *reinterpret_cast<const bf16x8*>((KB) + ak01 + (KOFF));                    \
        bf16x8 k10 = *reinterpret_cast<const bf16x8*>((KB) + ak10 + (KOFF));                    \
        bf16x8 k11 = *reinterpret_cast<const bf16x8*>((KB) + ak11 + (KOFF));                    \
        bf16x8 v0  = *reinterpret_cast<const bf16x8*>((VB) + (AV));                             \
        bf16x8 v1  = *reinterpret_cast<const bf16x8*>((VB) + (AV) + 1024);                      \
        bf16x8 v2  = *reinterpret_cast<const bf16x8*>((VB) + (AV) + 2048);                      \
        bf16x8 v3  = *reinterpret_cast<const bf16x8*>((VB) + (AV) + 3072);                      \
        f32x4 s0 = {}, s1 = {};                                                                 \
        s0 = __builtin_amdgcn_mfma_f32_16x16x32_bf16(k00, qf0, s0, 0, 0, 0);                    \
        s0 = __builtin_amdgcn_mfma_f32_16x16x32_bf16(k01, qf1, s0, 0, 0, 0);                    \
        s1 = __builtin_amdgcn_mfma_f32_16x16x32_bf16(k10, qf0, s1, 0, 0, 0);                    \
        s1 = __builtin_amdgcn_mfma_f32_16x16x32_bf16(k11, qf1, s1, 0, 0, 0);                    \
        bf16x8 pf;                                                                              \
        pf[0] = (__bf16)__builtin_amdgcn_exp2f(s0[0]);                                          \
        pf[1] = (__bf16)__builtin_amdgcn_exp2f(s0[1]);                                          \
        pf[2] = (__bf16)__builtin_amdgcn_exp2f(s0[2]);                                          \
        pf[3] = (__bf16)__builtin_amdgcn_exp2f(s0[3]);                                          \
        pf[4] = (__bf16)__builtin_amdgcn_exp2f(s1[0]);                                          \
        pf[5] = (__bf16)__builtin_amdgcn_exp2f(s1[1]);                                          \
        pf[6] = (__bf16)__builtin_amdgcn_exp2f(s1[2]);                                          \
        pf[7] = (__bf16)__builtin_amdgcn_exp2f(s1[3]);                                          \
        ors = __builtin_amdgcn_mfma_f32_16x16x32_bf16(pf, onesf, ors, 0, 0, 0);                 \
        o0 = __builtin_amdgcn_mfma_f32_16x16x32_bf16(pf, v0, o0, 0, 0, 0);                      \
        o1 = __builtin_amdgcn_mfma_f32_16x16x32_bf16(pf, v1, o1, 0, 0, 0);                      \
        o2 = __builtin_amdgcn_mfma_f32_16x16x32_bf16(pf, v2, o2, 0, 0, 0);                      \
        o3 = __builtin_amdgcn_mfma_f32_16x16x32_bf16(pf, v3, o3, 0, 0, 0);                      \
    }

    STAGE(0, 0)
    __syncthreads();

    for (int t = 0; t < 32; t += 2) {
        if (t + 1 < 32) { STAGE(1, (t + 1) * 64) }
        COMPUTE(Klds[0], Vlds[0], 0,    av0)
        COMPUTE(Klds[0], Vlds[0], 2048, av1)
        __syncthreads();
        if (t + 2 < 32) { STAGE(0, (t + 2) * 64) }
        COMPUTE(Klds[1], Vlds[1], 0,    av0)
        COMPUTE(Klds[1], Vlds[1], 2048, av1)
        __syncthreads();
    }
#undef STAGE
#undef COMPUTE

#pragma unroll
    for (int r = 0; r < 4; ++r) {
        float inv = 1.0f / ors[r];
        size_t row = ((size_t)b * N_ + qbase + lg * 4 + r) * QD_ + h * D_ + l15;
        AO[row +  0] = (__bf16)(o0[r] * inv);
        AO[row + 16] = (__bf16)(o1[r] * inv);
        AO[row + 32] = (__bf16)(o2[r] * inv);
        AO[row + 48] = (__bf16)(o3[r] * inv);
    }
}

// ---------------------------------------------------------------------------
extern "C" void kernel_launch(void* const* d_in, const int* in_sizes, int n_in,
                              void* d_out, int out_size, void* d_ws, size_t ws_size,
                              hipStream_t stream) {
    const float* x   = (const float*)d_in[0];
    const float* ctx = (const float*)d_in[1];
    const float* Wq  = (const float*)d_in[2];
    const float* Wk  = (const float*)d_in[3];
    const float* Wv  = (const float*)d_in[4];
    const float* Wo  = (const float*)d_in[5];

    char* ws = (char*)d_ws;
    __bf16* xb  = (__bf16*)(ws);                      // 0-8 MB
    __bf16* cb  = (__bf16*)(ws + (8u  << 20));        // 8-16 MB
    __bf16* Wtq = (__bf16*)(ws + (16u << 20));        // 16-18 MB
    __bf16* Wtk = (__bf16*)(ws + (18u << 20));        // 18-20
    __bf16* Wtv = (__bf16*)(ws + (20u << 20));        // 20-22
    __bf16* Wto = (__bf16*)(ws + (22u << 20));        // 22-24
    __bf16* Qb  = (__bf16*)(ws + (24u << 20));        // 24-32  [bh][2048][64], pre-scaled
    __bf16* Kb  = (__bf16*)(ws + (32u << 20));        // 32-40  [bh][2048][64]
    __bf16* Vt  = (__bf16*)(ws + (40u << 20));        // 40-48  [bh][64][2048]
    __bf16* AO  = (__bf16*)(ws + (48u << 20));        // 48-56  [4096][1024]

    prep<<<dim3(16, 16, 6), 256, 0, stream>>>(x, ctx, Wq, Wk, Wv, Wo,
                                              xb, cb, Wtq, Wtk, Wtv, Wto);
    gemm_qkv<<<dim3(32, 8, 3), 256, 0, stream>>>(xb, cb, Wtq, Wtk, Wtv, Qb, Kb, Vt);
    attn_kernel<<<512, 512, 0, stream>>>(Qb, Kb, Vt, AO);
    gemm_out<<<dim3(32, 16), 256, 0, stream>>>(AO, Wto, (float*)d_out);
}